// Round 3
// baseline (47.934 us; speedup 1.0000x reference)
//
#include <hip/hip_runtime.h>
#include <math.h>

// out[b,t,d] = X[b,t,d] + PE[t,d]
//   PE[t,2i]   = sin(t / 10000^(2i/d))
//   PE[t,2i+1] = cos(t / 10000^(2i/d))
// B=8, T=4096, D=1024. Memory-bound: 128 MiB read + 128 MiB write.
//
// R2: non-temporal stores via clang ext_vector_type (the builtin rejects
// HIP_vector_type structs). Write stream has zero reuse; keeping it out of
// L2/L3 preserves Infinity-Cache residency of X (128 MiB < 256 MiB LLC).
// R0 counters: FETCH ~65 MB = half of X already LLC-resident, other half
// evicted by our own write allocations.

typedef float floatx4 __attribute__((ext_vector_type(4)));

__global__ __launch_bounds__(256) void pe_add_kernel(
    const float* __restrict__ X, float* __restrict__ out) {
    constexpr int B = 8, T = 4096, D = 1024;
    constexpr int D4 = D / 4;               // 256 float4 per row
    constexpr long long TD = (long long)T * D;

    const int idx = blockIdx.x * blockDim.x + threadIdx.x;  // 0 .. T*D/4-1
    const int t  = idx >> 8;                 // / D4
    const int c4 = idx & (D4 - 1);           // % D4
    const int d0 = c4 * 4;

    // inv_freq = 10000^(-2i/D) = exp2(-(2i/D) * log2(10000))
    const float L2_10000 = 13.287712379549449f;  // log2(10000)
    const float pos = (float)t;
    const float i0 = (float)(d0 >> 1);
    const float i1 = i0 + 1.0f;
    const float f0 = exp2f(-(2.0f * i0 / (float)D) * L2_10000);
    const float f1 = exp2f(-(2.0f * i1 / (float)D) * L2_10000);

    float s0, c0, s1, c1;
    sincosf(pos * f0, &s0, &c0);   // accurate arg reduction: pos*f0 up to 4095 rad
    sincosf(pos * f1, &s1, &c1);

    floatx4 pe;
    pe.x = s0; pe.y = c0; pe.z = s1; pe.w = c1;
    const long long base = (long long)t * D + d0;

    #pragma unroll
    for (int b = 0; b < B; ++b) {
        const long long off = (long long)b * TD + base;
        floatx4 x = *reinterpret_cast<const floatx4*>(X + off);
        x += pe;
        __builtin_nontemporal_store(x, reinterpret_cast<floatx4*>(out + off));
    }
}

extern "C" void kernel_launch(void* const* d_in, const int* in_sizes, int n_in,
                              void* d_out, int out_size, void* d_ws, size_t ws_size,
                              hipStream_t stream) {
    const float* X = (const float*)d_in[0];
    float* out = (float*)d_out;
    constexpr int T = 4096, D = 1024;
    constexpr int threads = 256;
    constexpr int total = T * D / 4;                 // one thread per float4 of a (t,d) row
    constexpr int blocks = (total + threads - 1) / threads;  // 4096
    pe_add_kernel<<<blocks, threads, 0, stream>>>(X, out);
}

// Round 4
// 43.140 us; speedup vs baseline: 1.1111x; 1.1111x over previous
//
#include <hip/hip_runtime.h>
#include <math.h>

// out[b,t,d] = X[b,t,d] + PE[t,d]
//   PE[t,2i]   = sin(t / 10000^(2i/d))
//   PE[t,2i+1] = cos(t / 10000^(2i/d))
// B=8, T=4096, D=1024. Memory-bound: 268 MB compulsory L2-boundary traffic.
//
// R4: revert nt stores (R3: neutral-to-regressive -> LLC read-hits don't buy
// time; fabric is the limiter). Split the batch loop 8->2 per thread
// (grid 4096 -> 16384 blocks) to shrink the scheduling-tail granularity,
// which is the remaining ~8% vs the 42.7us copy-ceiling floor.

typedef float floatx4 __attribute__((ext_vector_type(4)));

__global__ __launch_bounds__(256) void pe_add_kernel(
    const float* __restrict__ X, float* __restrict__ out) {
    constexpr int D = 1024;
    constexpr int D4 = D / 4;                      // 256 float4 per row
    constexpr int TD4 = 4096 * D4;                 // float4s per batch slice = 2^20
    constexpr long long TD = (long long)4096 * D;  // elements per batch slice

    const int tid = blockIdx.x * blockDim.x + threadIdx.x;  // 0 .. 4*TD4-1
    const int bp  = tid >> 20;                     // batch pair 0..3
    const int rem = tid & (TD4 - 1);               // (t, c4) within slice
    const int t   = rem >> 8;                      // / D4
    const int c4  = rem & (D4 - 1);                // % D4
    const int d0  = c4 * 4;

    // inv_freq = 10000^(-2i/D) = exp2(-(2i/D) * log2(10000))
    const float L2_10000 = 13.287712379549449f;    // log2(10000)
    const float pos = (float)t;
    const float i0 = (float)(d0 >> 1);
    const float i1 = i0 + 1.0f;
    const float f0 = exp2f(-(2.0f * i0 / (float)D) * L2_10000);
    const float f1 = exp2f(-(2.0f * i1 / (float)D) * L2_10000);

    float s0, c0, s1, c1;
    sincosf(pos * f0, &s0, &c0);   // accurate arg reduction: pos*f0 up to 4095 rad
    sincosf(pos * f1, &s1, &c1);

    floatx4 pe;
    pe.x = s0; pe.y = c0; pe.z = s1; pe.w = c1;

    const long long base = (long long)t * D + d0;
    const long long offA = (long long)bp * TD + base;        // batch bp
    const long long offB = (long long)(bp + 4) * TD + base;  // batch bp+4

    // issue both loads before either store (memory-level parallelism)
    floatx4 xa = *reinterpret_cast<const floatx4*>(X + offA);
    floatx4 xb = *reinterpret_cast<const floatx4*>(X + offB);
    xa += pe;
    xb += pe;
    *reinterpret_cast<floatx4*>(out + offA) = xa;
    *reinterpret_cast<floatx4*>(out + offB) = xb;
}

extern "C" void kernel_launch(void* const* d_in, const int* in_sizes, int n_in,
                              void* d_out, int out_size, void* d_ws, size_t ws_size,
                              hipStream_t stream) {
    const float* X = (const float*)d_in[0];
    float* out = (float*)d_out;
    constexpr int threads = 256;
    constexpr int total = 4 * 4096 * 256;            // 4 batch-pairs x T x D4
    constexpr int blocks = total / threads;          // 16384
    pe_add_kernel<<<blocks, threads, 0, stream>>>(X, out);
}